// Round 4
// baseline (1440.957 us; speedup 1.0000x reference)
//
#include <hip/hip_runtime.h>

typedef _Float16 hx8 __attribute__((ext_vector_type(8)));
typedef float    fx4 __attribute__((ext_vector_type(4)));

constexpr int T_ = 4608;   // tokens = 8*576
constexpr int D_ = 1024;
constexpr int H_ = 4096;
constexpr int C_ = 4096;
constexpr int E_ = 8;
constexpr int BM = 128;
constexpr int PADROWS = T_ * 2 + E_ * BM;   // 10240
constexpr int MAXTILES = PADROWS / BM;      // 80

// global -> LDS direct (16B/lane), dest = wave-uniform base + lane*16
__device__ __forceinline__ void gload16(const void* g, void* l) {
    __builtin_amdgcn_global_load_lds(
        (const __attribute__((address_space(1))) void*)g,
        (__attribute__((address_space(3))) void*)l, 16, 0, 0);
}

__device__ __forceinline__ hx8 pack8(fx4 a, fx4 b) {
    hx8 h;
    h[0]=(_Float16)a[0]; h[1]=(_Float16)a[1]; h[2]=(_Float16)a[2]; h[3]=(_Float16)a[3];
    h[4]=(_Float16)b[0]; h[5]=(_Float16)b[1]; h[6]=(_Float16)b[2]; h[7]=(_Float16)b[3];
    return h;
}

// ---------------- routing: logits, top-2, softmax, x -> fp16 ----------------
__global__ __launch_bounds__(256) void k_route(
    const float* __restrict__ x, const float* __restrict__ sw,
    const float* __restrict__ sb, _Float16* __restrict__ xh,
    int* __restrict__ meta, int* __restrict__ e0a, int* __restrict__ e1a,
    float* __restrict__ w0a, float* __restrict__ w1a)
{
    __shared__ float ssw[E_ * D_];
    const int tid = threadIdx.x;
    for (int i = tid; i < E_ * D_ / 4; i += 256)
        reinterpret_cast<fx4*>(ssw)[i] = reinterpret_cast<const fx4*>(sw)[i];
    __syncthreads();

    const int wid = tid >> 6, lane = tid & 63;
    const int t = blockIdx.x * 4 + wid;
    const float* xr = x + (size_t)t * D_;
    _Float16* xhr = xh + (size_t)t * D_;

    float acc[E_] = {};
    for (int i = lane; i < D_; i += 64) {
        float xv = xr[i];
        xhr[i] = (_Float16)xv;
        #pragma unroll
        for (int e = 0; e < E_; e++) acc[e] += xv * ssw[e * D_ + i];
    }
    #pragma unroll
    for (int e = 0; e < E_; e++) {
        float v = acc[e];
        #pragma unroll
        for (int o = 32; o > 0; o >>= 1) v += __shfl_xor(v, o, 64);
        acc[e] = v;
    }
    if (lane == 0) {
        float l[E_];
        #pragma unroll
        for (int e = 0; e < E_; e++) l[e] = acc[e] + sb[e];
        int b0 = 0; float v0 = l[0];
        #pragma unroll
        for (int e = 1; e < E_; e++) if (l[e] > v0) { v0 = l[e]; b0 = e; }
        int b1 = -1; float v1 = -3.4e38f;
        #pragma unroll
        for (int e = 0; e < E_; e++) if (e != b0 && l[e] > v1) { v1 = l[e]; b1 = e; }
        float r = __expf(v1 - v0);
        float inv = 1.f / (1.f + r);
        e0a[t] = b0; e1a[t] = b1; w0a[t] = inv; w1a[t] = r * inv;
        atomicAdd(&meta[b0], 1);
        atomicAdd(&meta[b1], 1);
    }
}

// ---------------- scan: padded offsets + rowtile->expert map ----------------
__global__ void k_scan(int* meta)
{
    if (threadIdx.x == 0) {
        int off = 0;
        for (int e = 0; e < E_; e++) {
            meta[16 + e] = off;
            off += ((meta[e] + BM - 1) / BM) * BM;
        }
        meta[24] = off;
        meta[25] = off / BM;
        int rt = 0;
        for (int e = 0; e < E_; e++) {
            int nt = (meta[e] + BM - 1) / BM;
            for (int i = 0; i < nt; i++) meta[32 + rt++] = e;
        }
    }
}

__global__ void k_scatter(int* __restrict__ meta,
                          const int* __restrict__ e0a, const int* __restrict__ e1a,
                          const float* __restrict__ w0a, const float* __restrict__ w1a,
                          int* __restrict__ tok, float* __restrict__ gate,
                          int* __restrict__ inv)
{
    int t = blockIdx.x * 256 + threadIdx.x;
    if (t >= T_) return;
    int* cursors = meta + 8;
    const int* padoff = meta + 16;
    int e0 = e0a[t];
    int s0 = atomicAdd(&cursors[e0], 1);
    int p0 = padoff[e0] + s0;
    tok[p0] = t; gate[p0] = w0a[t]; inv[2 * t] = p0;
    int e1 = e1a[t];
    int s1 = atomicAdd(&cursors[e1], 1);
    int p1 = padoff[e1] + s1;
    tok[p1] = t; gate[p1] = w1a[t]; inv[2 * t + 1] = p1;
}

// ---------------- GEMM1: h = silu(x W1^T + b1) * (x W3^T + b3) ----------------
// 128 rows x 64 hcols, dual-B, BK=64, double-buffered pipeline, direct fp32 B.
__global__ __launch_bounds__(256, 2) void k_gemm1(
    const _Float16* __restrict__ xh,
    const float* __restrict__ w1, const float* __restrict__ b1,
    const float* __restrict__ w3, const float* __restrict__ b3,
    const int* __restrict__ meta, const int* __restrict__ tok,
    _Float16* __restrict__ hbuf)
{
    const int rt = blockIdx.y;
    if (rt >= meta[25]) return;
    const int e = meta[32 + rt];
    const int n_e = meta[e];
    const int prow0 = rt * BM;
    const int row0 = prow0 - meta[16 + e];
    const int col0 = blockIdx.x * 64;

    __shared__ _Float16 sA[2][128 * 64];
    __shared__ _Float16 sB1[2][64 * 64];
    __shared__ _Float16 sB3[2][64 * 64];

    const int tid = threadIdx.x, w = tid >> 6, l = tid & 63;
    // A staging via gload_lds (4 wave-insts), pre-swizzled source col
    const int lrow = l >> 3, lcolh = 8 * ((l & 7) ^ lrow);
    const _Float16* aSrc[4];
    int aOff[4];
    #pragma unroll
    for (int i = 0; i < 4; i++) {
        const int c = w * 4 + i;
        const int t = tok[prow0 + c * 8 + lrow];   // pad rows -> token 0 (memset)
        aSrc[i] = xh + (size_t)t * D_ + lcolh;
        aOff[i] = c * 512;
    }
    // B staging (reg): row br (hcol), 16 floats at col bc
    const int br = tid >> 2, bc = (tid & 3) * 16;
    const float* p1 = w1 + ((size_t)e * H_ + col0 + br) * D_ + bc;
    const float* p3 = w3 + ((size_t)e * H_ + col0 + br) * D_ + bc;
    const int bws0 = br * 64 + ((bc)     ^ ((br & 7) << 3));
    const int bws1 = br * 64 + ((bc + 8) ^ ((br & 7) << 3));

    const int wr = (w >> 1) * 64, wc = (w & 1) * 32;
    const int fr = l & 15, q = l >> 4;

    fx4 r1[4], r3[4];
    fx4 acc1[4][2] = {}, acc3[4][2] = {};

    #define G1_LOADB(kk)                                            \
        _Pragma("unroll")                                           \
        for (int i = 0; i < 4; i++) {                               \
            r1[i] = *(const fx4*)(p1 + (kk) + 4 * i);               \
            r3[i] = *(const fx4*)(p3 + (kk) + 4 * i);               \
        }
    #define G1_STAGEA(buf, kk)                                      \
        _Pragma("unroll")                                           \
        for (int i = 0; i < 4; i++) gload16(aSrc[i] + (kk), &sA[buf][aOff[i]]);
    #define G1_WRITEB(buf)                                          \
        *(hx8*)&sB1[buf][bws0] = pack8(r1[0], r1[1]);               \
        *(hx8*)&sB1[buf][bws1] = pack8(r1[2], r1[3]);               \
        *(hx8*)&sB3[buf][bws0] = pack8(r3[0], r3[1]);               \
        *(hx8*)&sB3[buf][bws1] = pack8(r3[2], r3[3]);
    #define G1_COMPUTE(buf)                                         \
        _Pragma("unroll")                                           \
        for (int ks = 0; ks < 2; ks++) {                            \
            const int kb = ks * 32 + q * 8;                         \
            hx8 af[4], bf1[2], bf3[2];                              \
            _Pragma("unroll")                                       \
            for (int mi = 0; mi < 4; mi++) {                        \
                const int R = wr + mi * 16 + fr;                    \
                af[mi] = *(const hx8*)&sA[buf][R * 64 + (kb ^ ((R & 7) << 3))]; \
            }                                                       \
            _Pragma("unroll")                                       \
            for (int ni = 0; ni < 2; ni++) {                        \
                const int R = wc + ni * 16 + fr;                    \
                bf1[ni] = *(const hx8*)&sB1[buf][R * 64 + (kb ^ ((R & 7) << 3))]; \
                bf3[ni] = *(const hx8*)&sB3[buf][R * 64 + (kb ^ ((R & 7) << 3))]; \
            }                                                       \
            _Pragma("unroll")                                       \
            for (int ni = 0; ni < 2; ni++)                          \
                _Pragma("unroll")                                   \
                for (int mi = 0; mi < 4; mi++) {                    \
                    acc1[mi][ni] = __builtin_amdgcn_mfma_f32_16x16x32_f16(af[mi], bf1[ni], acc1[mi][ni], 0, 0, 0); \
                    acc3[mi][ni] = __builtin_amdgcn_mfma_f32_16x16x32_f16(af[mi], bf3[ni], acc3[mi][ni], 0, 0, 0); \
                }                                                   \
        }

    // prologue: stage tile 0
    G1_LOADB(0)
    G1_STAGEA(0, 0)
    G1_WRITEB(0)
    __syncthreads();

    int cur = 0;
    for (int kk = 64; kk < D_; kk += 64) {
        G1_LOADB(kk)           // next-tile B loads in flight
        G1_STAGEA(cur ^ 1, kk) // next-tile A glds in flight
        G1_COMPUTE(cur)
        G1_WRITEB(cur ^ 1)     // waits only B loads
        __syncthreads();       // drains A glds + LDS writes
        cur ^= 1;
    }
    G1_COMPUTE(cur)

    #pragma unroll
    for (int ni = 0; ni < 2; ni++) {
        const int col = col0 + wc + ni * 16 + fr;
        const float bb1 = b1[(size_t)e * H_ + col];
        const float bb3 = b3[(size_t)e * H_ + col];
        #pragma unroll
        for (int mi = 0; mi < 4; mi++) {
            const int rbase = wr + mi * 16 + q * 4;
            #pragma unroll
            for (int j = 0; j < 4; j++) {
                const int r = rbase + j;
                if (row0 + r < n_e) {
                    float v1 = acc1[mi][ni][j] + bb1;
                    float v3 = acc3[mi][ni][j] + bb3;
                    float hv = v1 * v3 / (1.f + __expf(-v1));
                    hbuf[(size_t)(prow0 + r) * H_ + col] = (_Float16)hv;
                }
            }
        }
    }
}

// ---------------- GEMM2: part = h W2^T + b2 (fp16 partials) ----------------
// 128 rows x 128 cols, BK=64, double-buffered pipeline, direct fp32 W2.
__global__ __launch_bounds__(256, 2) void k_gemm2(
    const _Float16* __restrict__ hbuf, const float* __restrict__ w2,
    const float* __restrict__ b2, const int* __restrict__ meta,
    _Float16* __restrict__ part)
{
    const int rt = blockIdx.y;
    if (rt >= meta[25]) return;
    const int e = meta[32 + rt];
    const int prow0 = rt * BM;
    const int col0 = blockIdx.x * 128;

    __shared__ _Float16 sA[2][128 * 64];
    __shared__ _Float16 sB[2][128 * 64];

    const int tid = threadIdx.x, w = tid >> 6, l = tid & 63;
    const int lrow = l >> 3, lcolh = 8 * ((l & 7) ^ lrow);
    const _Float16* aSrc[4];
    int aOff[4];
    #pragma unroll
    for (int i = 0; i < 4; i++) {
        const int c = w * 4 + i;
        aSrc[i] = hbuf + (size_t)(prow0 + c * 8 + lrow) * H_ + lcolh;  // pad rows benign
        aOff[i] = c * 512;
    }
    // B staging (reg): row br (wcol), 32 floats at col bc
    const int br = tid >> 1, bc = (tid & 1) * 32;
    const float* pB = w2 + ((size_t)e * C_ + col0 + br) * H_ + bc;
    int bws[4];
    #pragma unroll
    for (int j = 0; j < 4; j++)
        bws[j] = br * 64 + ((bc + 8 * j) ^ ((br & 7) << 3));

    const int wr = (w >> 1) * 64, wc = (w & 1) * 64;
    const int fr = l & 15, q = l >> 4;

    fx4 rb[8];
    fx4 acc[4][4] = {};

    #define G2_LOADB(kk)                                            \
        _Pragma("unroll")                                           \
        for (int i = 0; i < 8; i++) rb[i] = *(const fx4*)(pB + (kk) + 4 * i);
    #define G2_STAGEA(buf, kk)                                      \
        _Pragma("unroll")                                           \
        for (int i = 0; i < 4; i++) gload16(aSrc[i] + (kk), &sA[buf][aOff[i]]);
    #define G2_WRITEB(buf)                                          \
        _Pragma("unroll")                                           \
        for (int j = 0; j < 4; j++)                                 \
            *(hx8*)&sB[buf][bws[j]] = pack8(rb[2 * j], rb[2 * j + 1]);
    #define G2_COMPUTE(buf)                                         \
        _Pragma("unroll")                                           \
        for (int ks = 0; ks < 2; ks++) {                            \
            const int kb = ks * 32 + q * 8;                         \
            hx8 af[4], bf[4];                                       \
            _Pragma("unroll")                                       \
            for (int mi = 0; mi < 4; mi++) {                        \
                const int R = wr + mi * 16 + fr;                    \
                af[mi] = *(const hx8*)&sA[buf][R * 64 + (kb ^ ((R & 7) << 3))]; \
            }                                                       \
            _Pragma("unroll")                                       \
            for (int ni = 0; ni < 4; ni++) {                        \
                const int R = wc + ni * 16 + fr;                    \
                bf[ni] = *(const hx8*)&sB[buf][R * 64 + (kb ^ ((R & 7) << 3))]; \
            }                                                       \
            _Pragma("unroll")                                       \
            for (int ni = 0; ni < 4; ni++)                          \
                _Pragma("unroll")                                   \
                for (int mi = 0; mi < 4; mi++)                      \
                    acc[mi][ni] = __builtin_amdgcn_mfma_f32_16x16x32_f16(af[mi], bf[ni], acc[mi][ni], 0, 0, 0); \
        }

    G2_LOADB(0)
    G2_STAGEA(0, 0)
    G2_WRITEB(0)
    __syncthreads();

    int cur = 0;
    for (int kk = 64; kk < H_; kk += 64) {
        G2_LOADB(kk)
        G2_STAGEA(cur ^ 1, kk)
        G2_COMPUTE(cur)
        G2_WRITEB(cur ^ 1)
        __syncthreads();
        cur ^= 1;
    }
    G2_COMPUTE(cur)

    #pragma unroll
    for (int ni = 0; ni < 4; ni++) {
        const int col = col0 + wc + ni * 16 + fr;
        const float bb = b2[(size_t)e * C_ + col];
        #pragma unroll
        for (int mi = 0; mi < 4; mi++) {
            const int rbase = wr + mi * 16 + q * 4;
            #pragma unroll
            for (int j = 0; j < 4; j++) {
                const int prow = prow0 + rbase + j;     // pad rows: in-bounds, never read
                part[(size_t)prow * C_ + col] = (_Float16)(acc[mi][ni][j] + bb);
            }
        }
    }
}

// ---------------- combine: out[t] = g0*part[inv0] + g1*part[inv1] ----------------
__global__ __launch_bounds__(256) void k_combine(
    const _Float16* __restrict__ part, const int* __restrict__ inv,
    const float* __restrict__ gate, float* __restrict__ out)
{
    const int bid = blockIdx.x;               // T_*2 blocks
    const int t = bid >> 1;
    const int c0 = ((bid & 1) << 11) + ((int)threadIdx.x << 3);
    const int p0 = inv[2 * t], p1 = inv[2 * t + 1];
    const float g0 = gate[p0], g1 = gate[p1];
    hx8 a = *(const hx8*)(part + (size_t)p0 * C_ + c0);
    hx8 b = *(const hx8*)(part + (size_t)p1 * C_ + c0);
    fx4 o0, o1;
    #pragma unroll
    for (int j = 0; j < 4; j++) {
        o0[j] = g0 * (float)a[j]     + g1 * (float)b[j];
        o1[j] = g0 * (float)a[4 + j] + g1 * (float)b[4 + j];
    }
    *(fx4*)(out + (size_t)t * C_ + c0)     = o0;
    *(fx4*)(out + (size_t)t * C_ + c0 + 4) = o1;
}

// ---------------- launch ----------------
extern "C" void kernel_launch(void* const* d_in, const int* in_sizes, int n_in,
                              void* d_out, int out_size, void* d_ws, size_t ws_size,
                              hipStream_t stream)
{
    const float* x  = (const float*)d_in[0];
    const float* sw = (const float*)d_in[1];
    const float* sb = (const float*)d_in[2];
    const float* w1 = (const float*)d_in[3];
    const float* b1 = (const float*)d_in[4];
    const float* w2 = (const float*)d_in[5];
    const float* b2 = (const float*)d_in[6];
    const float* w3 = (const float*)d_in[7];
    const float* b3 = (const float*)d_in[8];
    float* out = (float*)d_out;

    char* ws = (char*)d_ws;
    const size_t OFF_META = 0;
    const size_t OFF_E0   = 1024;
    const size_t OFF_E1   = OFF_E0 + 4 * (size_t)T_;
    const size_t OFF_W0   = OFF_E1 + 4 * (size_t)T_;
    const size_t OFF_W1A  = OFF_W0 + 4 * (size_t)T_;
    const size_t OFF_TOK  = OFF_W1A + 4 * (size_t)T_;
    const size_t OFF_GATE = OFF_TOK + 4 * (size_t)PADROWS;
    const size_t OFF_INV  = OFF_GATE + 4 * (size_t)PADROWS;
    const size_t OFF_XH   = OFF_INV + 8 * (size_t)T_;
    const size_t OFF_HBUF = OFF_XH + 2 * (size_t)T_ * D_;
    const size_t OFF_PART = OFF_HBUF + 2 * (size_t)PADROWS * H_;

    int*      meta  = (int*)(ws + OFF_META);
    int*      e0a   = (int*)(ws + OFF_E0);
    int*      e1a   = (int*)(ws + OFF_E1);
    float*    w0a   = (float*)(ws + OFF_W0);
    float*    w1a   = (float*)(ws + OFF_W1A);
    int*      tokb  = (int*)(ws + OFF_TOK);
    float*    gateb = (float*)(ws + OFF_GATE);
    int*      invb  = (int*)(ws + OFF_INV);
    _Float16* xh    = (_Float16*)(ws + OFF_XH);
    _Float16* hbuf  = (_Float16*)(ws + OFF_HBUF);
    _Float16* partb = (_Float16*)(ws + OFF_PART);

    hipMemsetAsync(meta, 0, 1024, stream);
    hipMemsetAsync(tokb, 0, 4 * (size_t)PADROWS, stream);

    k_route<<<T_ / 4, 256, 0, stream>>>(x, sw, sb, xh, meta, e0a, e1a, w0a, w1a);
    k_scan<<<1, 1, 0, stream>>>(meta);
    k_scatter<<<(T_ + 255) / 256, 256, 0, stream>>>(meta, e0a, e1a, w0a, w1a,
                                                    tokb, gateb, invb);
    k_gemm1<<<dim3(H_ / 64, MAXTILES), 256, 0, stream>>>(xh, w1, b1, w3, b3,
                                                         meta, tokb, hbuf);
    k_gemm2<<<dim3(C_ / 128, MAXTILES), 256, 0, stream>>>(hbuf, w2, b2, meta, partb);
    k_combine<<<T_ * 2, 256, 0, stream>>>(partb, invb, gateb, out);
}

// Round 5
// 1024.303 us; speedup vs baseline: 1.4068x; 1.4068x over previous
//
#include <hip/hip_runtime.h>

typedef _Float16 hx8 __attribute__((ext_vector_type(8)));
typedef float    fx4 __attribute__((ext_vector_type(4)));

constexpr int T_ = 4608;   // tokens = 8*576
constexpr int D_ = 1024;
constexpr int H_ = 4096;
constexpr int C_ = 4096;
constexpr int E_ = 8;
constexpr int PADROWS = T_ * 2 + E_ * 256;   // 11264 (256-padded buckets)
constexpr int MAXRT128 = 80;
constexpr int MAXRT256 = 44;

constexpr int NB_ROUTE = T_ / 4;             // 1152
constexpr int NB_CVT1  = 1024;
constexpr int NB_CVT3  = 1024;
constexpr int NB_A     = NB_ROUTE + NB_CVT1 + NB_CVT3;

// global -> LDS direct (16B/lane), dest = wave-uniform base + lane*16
__device__ __forceinline__ void gload16(const void* g, void* l) {
    __builtin_amdgcn_global_load_lds(
        (const __attribute__((address_space(1))) void*)g,
        (__attribute__((address_space(3))) void*)l, 16, 0, 0);
}

// grid-strided fp32 -> fp16 convert over n8 hx8-chunks
__device__ __forceinline__ void cvt_stride(const float* __restrict__ s,
                                           _Float16* __restrict__ d,
                                           int n8, int bidx, int nblocks)
{
    const fx4* s4 = (const fx4*)s;
    hx8* d8 = (hx8*)d;
    const int stride = nblocks * 256;
    for (int i = bidx * 256 + (int)threadIdx.x; i < n8; i += stride) {
        fx4 a = s4[2 * (size_t)i], b = s4[2 * (size_t)i + 1];
        hx8 h;
        h[0]=(_Float16)a[0]; h[1]=(_Float16)a[1]; h[2]=(_Float16)a[2]; h[3]=(_Float16)a[3];
        h[4]=(_Float16)b[0]; h[5]=(_Float16)b[1]; h[6]=(_Float16)b[2]; h[7]=(_Float16)b[3];
        d8[i] = h;
    }
}

__global__ __launch_bounds__(256) void k_cvt(const float* __restrict__ s,
                                             _Float16* __restrict__ d, int n8)
{
    cvt_stride(s, d, n8, blockIdx.x, gridDim.x);
}

// ---------------- launch A: routing + cvt W1/W3 ----------------
__global__ __launch_bounds__(256) void k_routecvt(
    const float* __restrict__ x, const float* __restrict__ sw,
    const float* __restrict__ sb,
    const float* __restrict__ w1, _Float16* __restrict__ w1h,
    const float* __restrict__ w3, _Float16* __restrict__ w3h,
    _Float16* __restrict__ xh,
    int* __restrict__ meta, int* __restrict__ e0a, int* __restrict__ e1a,
    float* __restrict__ w0a, float* __restrict__ w1a)
{
    __shared__ float ssw[E_ * D_];
    const int id = blockIdx.x;
    const int tid = threadIdx.x;

    if (id >= NB_ROUTE) {
        if (id < NB_ROUTE + NB_CVT1)
            cvt_stride(w1, w1h, E_ * H_ * D_ / 8, id - NB_ROUTE, NB_CVT1);
        else
            cvt_stride(w3, w3h, E_ * H_ * D_ / 8, id - NB_ROUTE - NB_CVT1, NB_CVT3);
        return;
    }

    for (int i = tid; i < E_ * D_ / 4; i += 256)
        reinterpret_cast<fx4*>(ssw)[i] = reinterpret_cast<const fx4*>(sw)[i];
    __syncthreads();

    const int wid = tid >> 6, lane = tid & 63;
    const int t = id * 4 + wid;
    const float* xr = x + (size_t)t * D_;
    _Float16* xhr = xh + (size_t)t * D_;

    float acc[E_] = {};
    for (int i = lane; i < D_; i += 64) {
        float xv = xr[i];
        xhr[i] = (_Float16)xv;
        #pragma unroll
        for (int e = 0; e < E_; e++) acc[e] += xv * ssw[e * D_ + i];
    }
    #pragma unroll
    for (int e = 0; e < E_; e++) {
        float v = acc[e];
        #pragma unroll
        for (int o = 32; o > 0; o >>= 1) v += __shfl_xor(v, o, 64);
        acc[e] = v;
    }
    if (lane == 0) {
        float l[E_];
        #pragma unroll
        for (int e = 0; e < E_; e++) l[e] = acc[e] + sb[e];
        int b0 = 0; float v0 = l[0];
        #pragma unroll
        for (int e = 1; e < E_; e++) if (l[e] > v0) { v0 = l[e]; b0 = e; }
        int b1 = -1; float v1 = -3.4e38f;
        #pragma unroll
        for (int e = 0; e < E_; e++) if (e != b0 && l[e] > v1) { v1 = l[e]; b1 = e; }
        float r = __expf(v1 - v0);
        float inv = 1.f / (1.f + r);
        e0a[t] = b0; e1a[t] = b1; w0a[t] = inv; w1a[t] = r * inv;
        atomicAdd(&meta[b0], 1);
        atomicAdd(&meta[b1], 1);
    }
}

// ---------------- scan: 256-padded offsets + rowtile maps ----------------
// meta: [0..7]=cnt [8..15]=cursor [16..23]=padoff [24]=totalrows [25]=RT128
// [26]=RT256 [32..111]=map128 expert [112..191]=map128 tileidx [192..235]=map256 expert
__global__ void k_scan(int* meta)
{
    if (threadIdx.x == 0) {
        int off = 0, rt128 = 0, rt256 = 0;
        for (int e = 0; e < E_; e++) {
            meta[16 + e] = off;
            int n = meta[e];
            int t128 = (n + 127) / 128;
            int t256 = (n + 255) / 256;
            for (int i = 0; i < t128; i++) { meta[32 + rt128] = e; meta[112 + rt128] = i; rt128++; }
            for (int i = 0; i < t256; i++) { meta[192 + rt256] = e; rt256++; }
            off += t256 * 256;
        }
        meta[24] = off;
        meta[25] = rt128;
        meta[26] = rt256;
    }
}

__global__ void k_scatter(int* __restrict__ meta,
                          const int* __restrict__ e0a, const int* __restrict__ e1a,
                          const float* __restrict__ w0a, const float* __restrict__ w1a,
                          int* __restrict__ tok, float* __restrict__ gate,
                          int* __restrict__ inv)
{
    int t = blockIdx.x * 256 + threadIdx.x;
    if (t >= T_) return;
    int* cursors = meta + 8;
    const int* padoff = meta + 16;
    int e0 = e0a[t];
    int s0 = atomicAdd(&cursors[e0], 1);
    int p0 = padoff[e0] + s0;
    tok[p0] = t; gate[p0] = w0a[t]; inv[2 * t] = p0;
    int e1 = e1a[t];
    int s1 = atomicAdd(&cursors[e1], 1);
    int p1 = padoff[e1] + s1;
    tok[p1] = t; gate[p1] = w1a[t]; inv[2 * t + 1] = p1;
}

// ---------------- GEMM1: h = silu(x W1^T + b1) * (x W3^T + b3) ----------------
// 128 rows x 64 hcols, dual-B, BK=64, fp16 weights via gload_lds (round-2 proven body)
__global__ __launch_bounds__(256) void k_gemm1(
    const _Float16* __restrict__ xh,
    const _Float16* __restrict__ w1h, const float* __restrict__ b1,
    const _Float16* __restrict__ w3h, const float* __restrict__ b3,
    const int* __restrict__ meta, const int* __restrict__ tok,
    _Float16* __restrict__ hbuf)
{
    const int rt = blockIdx.y;
    if (rt >= meta[25]) return;
    const int e = meta[32 + rt];
    const int idx = meta[112 + rt];
    const int n_e = meta[e];
    const int row0 = idx * 128;
    const int prow0 = meta[16 + e] + row0;
    const int col0 = blockIdx.x * 64;

    __shared__ _Float16 sA[128 * 64];
    __shared__ _Float16 sB1[64 * 64];
    __shared__ _Float16 sB3[64 * 64];

    const int tid = threadIdx.x;
    const int w = tid >> 6, l = tid & 63;
    const int lrow = l >> 3;
    const int lcolh = 8 * ((l & 7) ^ lrow);   // pre-swizzled source col (halves)

    const _Float16* aSrc[4];
    int aOff[4];
    #pragma unroll
    for (int i = 0; i < 4; i++) {
        const int c = w * 4 + i;
        const int t = tok[prow0 + c * 8 + lrow];   // pad rows -> token 0 (memset)
        aSrc[i] = xh + (size_t)t * D_ + lcolh;
        aOff[i] = c * 512;
    }
    const _Float16 *b1Src[2], *b3Src[2];
    _Float16 *b1Dst[2], *b3Dst[2];
    #pragma unroll
    for (int i = 0; i < 2; i++) {
        const int c = w * 2 + i;
        const int r = c * 8 + lrow;
        b1Src[i] = w1h + ((size_t)e * H_ + col0 + r) * D_ + lcolh;
        b3Src[i] = w3h + ((size_t)e * H_ + col0 + r) * D_ + lcolh;
        b1Dst[i] = &sB1[c * 512];
        b3Dst[i] = &sB3[c * 512];
    }

    const int wr = (w >> 1) * 64, wc = (w & 1) * 32;
    const int fr = l & 15, q = l >> 4;

    fx4 acc1[4][2] = {}, acc3[4][2] = {};

    for (int kk = 0; kk < D_; kk += 64) {
        __syncthreads();
        #pragma unroll
        for (int i = 0; i < 4; i++) gload16(aSrc[i] + kk, &sA[aOff[i]]);
        #pragma unroll
        for (int i = 0; i < 2; i++) {
            gload16(b1Src[i] + kk, b1Dst[i]);
            gload16(b3Src[i] + kk, b3Dst[i]);
        }
        __syncthreads();
        #pragma unroll
        for (int ks = 0; ks < 2; ks++) {
            const int kb = ks * 32 + q * 8;
            hx8 af[4], bf1[2], bf3[2];
            #pragma unroll
            for (int mi = 0; mi < 4; mi++) {
                const int R = wr + mi * 16 + fr;
                af[mi] = *(const hx8*)&sA[R * 64 + (kb ^ ((R & 7) << 3))];
            }
            #pragma unroll
            for (int ni = 0; ni < 2; ni++) {
                const int R = wc + ni * 16 + fr;
                bf1[ni] = *(const hx8*)&sB1[R * 64 + (kb ^ ((R & 7) << 3))];
                bf3[ni] = *(const hx8*)&sB3[R * 64 + (kb ^ ((R & 7) << 3))];
            }
            #pragma unroll
            for (int ni = 0; ni < 2; ni++)
                #pragma unroll
                for (int mi = 0; mi < 4; mi++) {
                    acc1[mi][ni] = __builtin_amdgcn_mfma_f32_16x16x32_f16(af[mi], bf1[ni], acc1[mi][ni], 0, 0, 0);
                    acc3[mi][ni] = __builtin_amdgcn_mfma_f32_16x16x32_f16(af[mi], bf3[ni], acc3[mi][ni], 0, 0, 0);
                }
        }
    }

    #pragma unroll
    for (int ni = 0; ni < 2; ni++) {
        const int col = col0 + wc + ni * 16 + fr;
        const float bb1 = b1[(size_t)e * H_ + col];
        const float bb3 = b3[(size_t)e * H_ + col];
        #pragma unroll
        for (int mi = 0; mi < 4; mi++) {
            const int rbase = wr + mi * 16 + q * 4;
            #pragma unroll
            for (int j = 0; j < 4; j++) {
                const int r = rbase + j;
                if (row0 + r < n_e) {
                    float v1 = acc1[mi][ni][j] + bb1;
                    float v3 = acc3[mi][ni][j] + bb3;
                    float hv = v1 * v3 / (1.f + __expf(-v1));
                    hbuf[(size_t)(prow0 + r) * H_ + col] = (_Float16)hv;
                }
            }
        }
    }
}

// ---------------- GEMM2: part = h W2^T + b2  (256x256 tile, counted pipeline) ----------------
// 512 thr / 8 waves (2M x 4N), BK=64, dbuf 128 KiB dynamic LDS, raw barriers + asm vmcnt.
__global__ __launch_bounds__(512, 2) void k_gemm2(
    const _Float16* __restrict__ hbuf, const _Float16* __restrict__ w2h,
    const float* __restrict__ b2, const int* __restrict__ meta,
    _Float16* __restrict__ part)
{
    // XCD swizzle: all 16 col-blocks of a rowtile share bid%8 -> same XCD L2 for A-tile
    const int b = blockIdx.x;
    const int g = b >> 3;
    const int r = (g >> 4) * 8 + (b & 7);
    const int c = g & 15;
    if (r >= meta[26]) return;
    const int e = meta[192 + r];
    const int prow0 = r * 256;
    const int col0 = c * 256;

    extern __shared__ _Float16 smem[];        // 128 KiB
    _Float16* sA = smem;                      // [2][256*64]
    _Float16* sB = smem + 2 * 256 * 64;       // [2][256*64]

    const int tid = threadIdx.x;
    const int w = tid >> 6, l = tid & 63;
    const int arow = tid >> 3;                // 0..63 (row within 64-row pass block)
    const int swizh = 8 * ((tid & 7) ^ (arow & 7));   // pre-swizzled source col (halves)
    const _Float16* aS = hbuf + (size_t)(prow0 + arow) * H_ + swizh;
    const _Float16* bS = w2h + ((size_t)e * C_ + col0 + arow) * H_ + swizh;
    const int wv8 = w * 8;

    const int wm = w >> 2, wn = w & 3;
    const int fr = l & 15, q4 = l >> 4;

    fx4 acc[8][4] = {};

    #define G2STAGE(buf, kk)                                                       \
        _Pragma("unroll")                                                          \
        for (int p = 0; p < 4; ++p) {                                              \
            gload16(aS + (size_t)(p * 64) * H_ + (kk), &sA[(buf) * 16384 + (p * 64 + wv8) * 64]); \
            gload16(bS + (size_t)(p * 64) * H_ + (kk), &sB[(buf) * 16384 + (p * 64 + wv8) * 64]); \
        }

    G2STAGE(0, 0)
    asm volatile("s_waitcnt vmcnt(0)" ::: "memory");
    __builtin_amdgcn_s_barrier();

    int cur = 0;
    for (int t = 0; t < H_ / 64; ++t) {
        if (t + 1 < H_ / 64) { G2STAGE(cur ^ 1, (t + 1) * 64) }   // next tile in flight
        hx8 bf[4][2];
        #pragma unroll
        for (int q = 0; q < 4; ++q) {                              // 4 sub-phases x 16 MFMA
            hx8 af[2][2];
            #pragma unroll
            for (int mi = 0; mi < 2; ++mi)
                #pragma unroll
                for (int kh = 0; kh < 2; ++kh) {
                    const int R = wm * 128 + q * 32 + mi * 16 + fr;
                    af[mi][kh] = *(const hx8*)&sA[cur * 16384 + R * 64 + 8 * (((kh << 2) + q4) ^ (R & 7))];
                }
            if (q == 0) {
                #pragma unroll
                for (int ni = 0; ni < 4; ++ni)
                    #pragma unroll
                    for (int kh = 0; kh < 2; ++kh) {
                        const int Rc = wn * 64 + ni * 16 + fr;
                        bf[ni][kh] = *(const hx8*)&sB[cur * 16384 + Rc * 64 + 8 * (((kh << 2) + q4) ^ (Rc & 7))];
                    }
            }
            __builtin_amdgcn_s_setprio(1);
            #pragma unroll
            for (int ni = 0; ni < 4; ++ni)
                #pragma unroll
                for (int mi = 0; mi < 2; ++mi) {
                    acc[q * 2 + mi][ni] = __builtin_amdgcn_mfma_f32_16x16x32_f16(af[mi][0], bf[ni][0], acc[q * 2 + mi][ni], 0, 0, 0);
                    acc[q * 2 + mi][ni] = __builtin_amdgcn_mfma_f32_16x16x32_f16(af[mi][1], bf[ni][1], acc[q * 2 + mi][ni], 0, 0, 0);
                }
            __builtin_amdgcn_s_setprio(0);
        }
        asm volatile("s_waitcnt vmcnt(0)" ::: "memory");   // next tile staged (had full K-tile to land)
        __builtin_amdgcn_s_barrier();
        cur ^= 1;
    }

    #pragma unroll
    for (int ni = 0; ni < 4; ++ni) {
        const int col = col0 + wn * 64 + ni * 16 + fr;
        const float bb = b2[(size_t)e * C_ + col];
        #pragma unroll
        for (int rf = 0; rf < 8; ++rf) {
            const int rowb = prow0 + wm * 128 + rf * 16 + q4 * 4;
            #pragma unroll
            for (int j = 0; j < 4; ++j)
                part[(size_t)(rowb + j) * C_ + col] = (_Float16)(acc[rf][ni][j] + bb);
        }
    }
    #undef G2STAGE
}

// ---------------- combine: out[t] = g0*part[inv0] + g1*part[inv1] ----------------
__global__ __launch_bounds__(256) void k_combine(
    const _Float16* __restrict__ part, const int* __restrict__ inv,
    const float* __restrict__ gate, float* __restrict__ out)
{
    const int bid = blockIdx.x;               // T_*2 blocks
    const int t = bid >> 1;
    const int c0 = ((bid & 1) << 11) + ((int)threadIdx.x << 3);
    const int p0 = inv[2 * t], p1 = inv[2 * t + 1];
    const float g0 = gate[p0], g1 = gate[p1];
    hx8 a = *(const hx8*)(part + (size_t)p0 * C_ + c0);
    hx8 b = *(const hx8*)(part + (size_t)p1 * C_ + c0);
    fx4 o0, o1;
    #pragma unroll
    for (int j = 0; j < 4; j++) {
        o0[j] = g0 * (float)a[j]     + g1 * (float)b[j];
        o1[j] = g0 * (float)a[4 + j] + g1 * (float)b[4 + j];
    }
    *(fx4*)(out + (size_t)t * C_ + c0)     = o0;
    *(fx4*)(out + (size_t)t * C_ + c0 + 4) = o1;
}

// ---------------- launch ----------------
extern "C" void kernel_launch(void* const* d_in, const int* in_sizes, int n_in,
                              void* d_out, int out_size, void* d_ws, size_t ws_size,
                              hipStream_t stream)
{
    const float* x  = (const float*)d_in[0];
    const float* sw = (const float*)d_in[1];
    const float* sb = (const float*)d_in[2];
    const float* w1 = (const float*)d_in[3];
    const float* b1 = (const float*)d_in[4];
    const float* w2 = (const float*)d_in[5];
    const float* b2 = (const float*)d_in[6];
    const float* w3 = (const float*)d_in[7];
    const float* b3 = (const float*)d_in[8];
    float* out = (float*)d_out;

    char* ws = (char*)d_ws;
    const size_t OFF_META = 0;                                    // 2048 B
    const size_t OFF_E0   = 2048;
    const size_t OFF_E1   = OFF_E0 + 4 * (size_t)T_;
    const size_t OFF_W0   = OFF_E1 + 4 * (size_t)T_;
    const size_t OFF_W1A  = OFF_W0 + 4 * (size_t)T_;
    const size_t OFF_TOK  = OFF_W1A + 4 * (size_t)T_;
    const size_t OFF_GATE = OFF_TOK + 4 * (size_t)PADROWS;
    const size_t OFF_INV  = OFF_GATE + 4 * (size_t)PADROWS;
    const size_t OFF_XH   = OFF_INV + 8 * (size_t)T_;
    const size_t OFF_HBUF = OFF_XH + 2 * (size_t)T_ * D_;
    // ALIAS region: w1h+w3h (live: route..gemm1) overlaps part (live: gemm2..combine)
    const size_t OFF_ALIAS = OFF_HBUF + 2 * (size_t)PADROWS * H_;
    const size_t SZ_ALIAS  = 4 * (size_t)E_ * H_ * D_;            // 128 MiB (w1h+w3h)
    const size_t OFF_W2H   = OFF_ALIAS + SZ_ALIAS;

    int*      meta  = (int*)(ws + OFF_META);
    int*      e0a   = (int*)(ws + OFF_E0);
    int*      e1a   = (int*)(ws + OFF_E1);
    float*    w0a   = (float*)(ws + OFF_W0);
    float*    w1a   = (float*)(ws + OFF_W1A);
    int*      tokb  = (int*)(ws + OFF_TOK);
    float*    gateb = (float*)(ws + OFF_GATE);
    int*      invb  = (int*)(ws + OFF_INV);
    _Float16* xh    = (_Float16*)(ws + OFF_XH);
    _Float16* hbuf  = (_Float16*)(ws + OFF_HBUF);
    _Float16* w1h   = (_Float16*)(ws + OFF_ALIAS);
    _Float16* w3h   = (_Float16*)(ws + OFF_ALIAS + 2 * (size_t)E_ * H_ * D_);
    _Float16* partb = (_Float16*)(ws + OFF_ALIAS);                // reuses w1h/w3h space
    _Float16* w2h   = (_Float16*)(ws + OFF_W2H);

    hipMemsetAsync(meta, 0, 2048, stream);
    hipMemsetAsync(tokb, 0, 4 * (size_t)PADROWS, stream);

    k_routecvt<<<NB_A, 256, 0, stream>>>(x, sw, sb, w1, w1h, w3, w3h, xh,
                                         meta, e0a, e1a, w0a, w1a);
    k_scan<<<1, 1, 0, stream>>>(meta);
    k_scatter<<<(T_ + 255) / 256, 256, 0, stream>>>(meta, e0a, e1a, w0a, w1a,
                                                    tokb, gateb, invb);
    k_gemm1<<<dim3(H_ / 64, MAXRT128), 256, 0, stream>>>(xh, w1h, b1, w3h, b3,
                                                         meta, tokb, hbuf);
    k_cvt<<<4096, 256, 0, stream>>>(w2, w2h, E_ * C_ * H_ / 8);
    k_gemm2<<<8 * 16 * ((MAXRT256 + 7) / 8), 512, 131072, stream>>>(hbuf, w2h, b2,
                                                                    meta, partb);
    k_combine<<<T_ * 2, 256, 0, stream>>>(partb, invb, gateb, out);
}

// Round 7
// 960.246 us; speedup vs baseline: 1.5006x; 1.0667x over previous
//
#include <hip/hip_runtime.h>

typedef _Float16 hx8 __attribute__((ext_vector_type(8)));
typedef float    fx4 __attribute__((ext_vector_type(4)));

constexpr int T_ = 4608;   // tokens = 8*576
constexpr int D_ = 1024;
constexpr int H_ = 4096;
constexpr int C_ = 4096;
constexpr int E_ = 8;
constexpr int PADROWS = T_ * 2 + E_ * 256;   // 11264 (256-padded buckets)
constexpr int MAXRT256 = 44;

constexpr int NB_ROUTE = T_ / 4;             // 1152
constexpr int NB_CVT1  = 1024;
constexpr int NB_CVT3  = 1024;
constexpr int NB_CVT2  = 4096;
constexpr int NB_A     = NB_ROUTE + NB_CVT1 + NB_CVT3 + NB_CVT2;

// global -> LDS direct (16B/lane), dest = wave-uniform base + lane*16
__device__ __forceinline__ void gload16(const void* g, void* l) {
    __builtin_amdgcn_global_load_lds(
        (const __attribute__((address_space(1))) void*)g,
        (__attribute__((address_space(3))) void*)l, 16, 0, 0);
}

// grid-strided fp32 -> fp16 convert over n8 hx8-chunks
__device__ __forceinline__ void cvt_stride(const float* __restrict__ s,
                                           _Float16* __restrict__ d,
                                           int n8, int bidx, int nblocks)
{
    const fx4* s4 = (const fx4*)s;
    hx8* d8 = (hx8*)d;
    const int stride = nblocks * 256;
    for (int i = bidx * 256 + (int)threadIdx.x; i < n8; i += stride) {
        fx4 a = s4[2 * (size_t)i], b = s4[2 * (size_t)i + 1];
        hx8 h;
        h[0]=(_Float16)a[0]; h[1]=(_Float16)a[1]; h[2]=(_Float16)a[2]; h[3]=(_Float16)a[3];
        h[4]=(_Float16)b[0]; h[5]=(_Float16)b[1]; h[6]=(_Float16)b[2]; h[7]=(_Float16)b[3];
        d8[i] = h;
    }
}

// ---------------- launch A: routing + cvt W1/W3/W2 ----------------
__global__ __launch_bounds__(256) void k_routecvt(
    const float* __restrict__ x, const float* __restrict__ sw,
    const float* __restrict__ sb,
    const float* __restrict__ w1, _Float16* __restrict__ w1h,
    const float* __restrict__ w3, _Float16* __restrict__ w3h,
    const float* __restrict__ w2, _Float16* __restrict__ w2h,
    _Float16* __restrict__ xh,
    int* __restrict__ meta, int* __restrict__ e0a, int* __restrict__ e1a,
    float* __restrict__ w0a, float* __restrict__ w1a)
{
    __shared__ float ssw[E_ * D_];
    const int id = blockIdx.x;
    const int tid = threadIdx.x;

    if (id >= NB_ROUTE) {
        const int cid = id - NB_ROUTE;
        if (cid < NB_CVT1)
            cvt_stride(w1, w1h, E_ * H_ * D_ / 8, cid, NB_CVT1);
        else if (cid < NB_CVT1 + NB_CVT3)
            cvt_stride(w3, w3h, E_ * H_ * D_ / 8, cid - NB_CVT1, NB_CVT3);
        else
            cvt_stride(w2, w2h, E_ * C_ * H_ / 8, cid - NB_CVT1 - NB_CVT3, NB_CVT2);
        return;
    }

    for (int i = tid; i < E_ * D_ / 4; i += 256)
        reinterpret_cast<fx4*>(ssw)[i] = reinterpret_cast<const fx4*>(sw)[i];
    __syncthreads();

    const int wid = tid >> 6, lane = tid & 63;
    const int t = id * 4 + wid;
    const float* xr = x + (size_t)t * D_;
    _Float16* xhr = xh + (size_t)t * D_;

    float acc[E_] = {};
    for (int i = lane; i < D_; i += 64) {
        float xv = xr[i];
        xhr[i] = (_Float16)xv;
        #pragma unroll
        for (int e = 0; e < E_; e++) acc[e] += xv * ssw[e * D_ + i];
    }
    #pragma unroll
    for (int e = 0; e < E_; e++) {
        float v = acc[e];
        #pragma unroll
        for (int o = 32; o > 0; o >>= 1) v += __shfl_xor(v, o, 64);
        acc[e] = v;
    }
    if (lane == 0) {
        float l[E_];
        #pragma unroll
        for (int e = 0; e < E_; e++) l[e] = acc[e] + sb[e];
        int b0 = 0; float v0 = l[0];
        #pragma unroll
        for (int e = 1; e < E_; e++) if (l[e] > v0) { v0 = l[e]; b0 = e; }
        int b1 = -1; float v1 = -3.4e38f;
        #pragma unroll
        for (int e = 0; e < E_; e++) if (e != b0 && l[e] > v1) { v1 = l[e]; b1 = e; }
        float r = __expf(v1 - v0);
        float inv = 1.f / (1.f + r);
        e0a[t] = b0; e1a[t] = b1; w0a[t] = inv; w1a[t] = r * inv;
        atomicAdd(&meta[b0], 1);
        atomicAdd(&meta[b1], 1);
    }
}

// ---------------- scan: 256-padded offsets + rowtile map ----------------
// meta: [0..7]=cnt [8..15]=cursor [16..23]=padoff [24]=rows [26]=RT256 [192..235]=map256
__global__ void k_scan(int* meta)
{
    if (threadIdx.x == 0) {
        int off = 0, rt256 = 0;
        for (int e = 0; e < E_; e++) {
            meta[16 + e] = off;
            int t256 = (meta[e] + 255) / 256;
            for (int i = 0; i < t256; i++) meta[192 + rt256++] = e;
            off += t256 * 256;
        }
        meta[24] = off;
        meta[26] = rt256;
    }
}

__global__ void k_scatter(int* __restrict__ meta,
                          const int* __restrict__ e0a, const int* __restrict__ e1a,
                          const float* __restrict__ w0a, const float* __restrict__ w1a,
                          int* __restrict__ tok, float* __restrict__ gate,
                          int* __restrict__ inv)
{
    int t = blockIdx.x * 256 + threadIdx.x;
    if (t >= T_) return;
    int* cursors = meta + 8;
    const int* padoff = meta + 16;
    int e0 = e0a[t];
    int s0 = atomicAdd(&cursors[e0], 1);
    int p0 = padoff[e0] + s0;
    tok[p0] = t; gate[p0] = w0a[t]; inv[2 * t] = p0;
    int e1 = e1a[t];
    int s1 = atomicAdd(&cursors[e1], 1);
    int p1 = padoff[e1] + s1;
    tok[p1] = t; gate[p1] = w1a[t]; inv[2 * t + 1] = p1;
}

// ---------------- GEMM1: h = silu(x W1^T + b1) * (x W3^T + b3) ----------------
// 256 rows x 128 hcols (x2 matrices), BK=64, 512 thr / 8 waves, dbuf 128 KiB LDS,
// counted pipeline (gemm2-proven skeleton).
__global__ __launch_bounds__(512, 2) void k_gemm1(
    const _Float16* __restrict__ xh,
    const _Float16* __restrict__ w1h, const float* __restrict__ b1,
    const _Float16* __restrict__ w3h, const float* __restrict__ b3,
    const int* __restrict__ meta, const int* __restrict__ tok,
    _Float16* __restrict__ hbuf)
{
    // XCD swizzle: 32 col-blocks of a rowtile share bid%8 -> same XCD L2 for A-tile
    const int b = blockIdx.x;
    const int g = b >> 3;
    const int r = (g >> 5) * 8 + (b & 7);
    const int c = g & 31;
    if (r >= meta[26]) return;
    const int e = meta[192 + r];
    const int prow0 = r * 256;
    const int col0 = c * 128;

    extern __shared__ _Float16 smem[];        // 128 KiB
    _Float16* sA  = smem;                     // [2][256*64]
    _Float16* sB1 = smem + 2 * 256 * 64;      // [2][128*64]
    _Float16* sB3 = sB1 + 2 * 128 * 64;       // [2][128*64]

    const int tid = threadIdx.x;
    const int w = tid >> 6, l = tid & 63;
    const int arow = tid >> 3;                // 0..63
    const int swizh = 8 * ((tid & 7) ^ (arow & 7));
    const int wv8 = w * 8;

    const _Float16* aSrc[4];
    #pragma unroll
    for (int p = 0; p < 4; ++p) {
        const int t = tok[prow0 + p * 64 + arow];   // pad rows -> token 0 (memset)
        aSrc[p] = xh + (size_t)t * D_ + swizh;
    }
    const _Float16* b1S = w1h + ((size_t)e * H_ + col0 + arow) * D_ + swizh;
    const _Float16* b3S = w3h + ((size_t)e * H_ + col0 + arow) * D_ + swizh;

    const int wm = w >> 2, wn = w & 3;
    const int fr = l & 15, q4 = l >> 4;

    fx4 acc1[8][2] = {}, acc3[8][2] = {};

    #define G1STAGE(buf, kk)                                                        \
        _Pragma("unroll")                                                           \
        for (int p = 0; p < 4; ++p)                                                 \
            gload16(aSrc[p] + (kk), &sA[(buf) * 16384 + (p * 64 + wv8) * 64]);      \
        _Pragma("unroll")                                                           \
        for (int p = 0; p < 2; ++p) {                                               \
            gload16(b1S + (size_t)(p * 64) * D_ + (kk), &sB1[(buf) * 8192 + (p * 64 + wv8) * 64]); \
            gload16(b3S + (size_t)(p * 64) * D_ + (kk), &sB3[(buf) * 8192 + (p * 64 + wv8) * 64]); \
        }

    G1STAGE(0, 0)
    asm volatile("s_waitcnt vmcnt(0)" ::: "memory");
    __builtin_amdgcn_s_barrier();

    int cur = 0;
    for (int t = 0; t < D_ / 64; ++t) {
        if (t + 1 < D_ / 64) { G1STAGE(cur ^ 1, (t + 1) * 64) }
        hx8 bf1[2][2], bf3[2][2];
        #pragma unroll
        for (int q = 0; q < 4; ++q) {
            hx8 af[2][2];
            #pragma unroll
            for (int mi = 0; mi < 2; ++mi)
                #pragma unroll
                for (int kh = 0; kh < 2; ++kh) {
                    const int R = wm * 128 + q * 32 + mi * 16 + fr;
                    af[mi][kh] = *(const hx8*)&sA[cur * 16384 + R * 64 + 8 * (((kh << 2) + q4) ^ (R & 7))];
                }
            if (q == 0) {
                #pragma unroll
                for (int ni = 0; ni < 2; ++ni)
                    #pragma unroll
                    for (int kh = 0; kh < 2; ++kh) {
                        const int Rc = wn * 32 + ni * 16 + fr;
                        bf1[ni][kh] = *(const hx8*)&sB1[cur * 8192 + Rc * 64 + 8 * (((kh << 2) + q4) ^ (Rc & 7))];
                        bf3[ni][kh] = *(const hx8*)&sB3[cur * 8192 + Rc * 64 + 8 * (((kh << 2) + q4) ^ (Rc & 7))];
                    }
            }
            __builtin_amdgcn_s_setprio(1);
            #pragma unroll
            for (int ni = 0; ni < 2; ++ni)
                #pragma unroll
                for (int mi = 0; mi < 2; ++mi) {
                    acc1[q * 2 + mi][ni] = __builtin_amdgcn_mfma_f32_16x16x32_f16(af[mi][0], bf1[ni][0], acc1[q * 2 + mi][ni], 0, 0, 0);
                    acc1[q * 2 + mi][ni] = __builtin_amdgcn_mfma_f32_16x16x32_f16(af[mi][1], bf1[ni][1], acc1[q * 2 + mi][ni], 0, 0, 0);
                    acc3[q * 2 + mi][ni] = __builtin_amdgcn_mfma_f32_16x16x32_f16(af[mi][0], bf3[ni][0], acc3[q * 2 + mi][ni], 0, 0, 0);
                    acc3[q * 2 + mi][ni] = __builtin_amdgcn_mfma_f32_16x16x32_f16(af[mi][1], bf3[ni][1], acc3[q * 2 + mi][ni], 0, 0, 0);
                }
            __builtin_amdgcn_s_setprio(0);
        }
        asm volatile("s_waitcnt vmcnt(0)" ::: "memory");
        __builtin_amdgcn_s_barrier();
        cur ^= 1;
    }

    #pragma unroll
    for (int ni = 0; ni < 2; ++ni) {
        const int col = col0 + wn * 32 + ni * 16 + fr;
        const float bb1 = b1[(size_t)e * H_ + col];
        const float bb3 = b3[(size_t)e * H_ + col];
        #pragma unroll
        for (int rf = 0; rf < 8; ++rf) {
            const int rowb = prow0 + wm * 128 + rf * 16 + q4 * 4;
            #pragma unroll
            for (int j = 0; j < 4; ++j) {
                float v1 = acc1[rf][ni][j] + bb1;
                float v3 = acc3[rf][ni][j] + bb3;
                float hv = v1 * v3 / (1.f + __expf(-v1));
                hbuf[(size_t)(rowb + j) * H_ + col] = (_Float16)hv;  // pad rows: defined (token 0)
            }
        }
    }
    #undef G1STAGE
}

// ---------------- GEMM2: part = h W2^T + b2  (256x256 tile, counted pipeline) ----------------
__global__ __launch_bounds__(512, 2) void k_gemm2(
    const _Float16* __restrict__ hbuf, const _Float16* __restrict__ w2h,
    const float* __restrict__ b2, const int* __restrict__ meta,
    _Float16* __restrict__ part)
{
    const int b = blockIdx.x;
    const int g = b >> 3;
    const int r = (g >> 4) * 8 + (b & 7);
    const int c = g & 15;
    if (r >= meta[26]) return;
    const int e = meta[192 + r];
    const int prow0 = r * 256;
    const int col0 = c * 256;

    extern __shared__ _Float16 smem[];        // 128 KiB
    _Float16* sA = smem;                      // [2][256*64]
    _Float16* sB = smem + 2 * 256 * 64;       // [2][256*64]

    const int tid = threadIdx.x;
    const int w = tid >> 6, l = tid & 63;
    const int arow = tid >> 3;
    const int swizh = 8 * ((tid & 7) ^ (arow & 7));
    const _Float16* aS = hbuf + (size_t)(prow0 + arow) * H_ + swizh;
    const _Float16* bS = w2h + ((size_t)e * C_ + col0 + arow) * H_ + swizh;
    const int wv8 = w * 8;

    const int wm = w >> 2, wn = w & 3;
    const int fr = l & 15, q4 = l >> 4;

    fx4 acc[8][4] = {};

    #define G2STAGE(buf, kk)                                                       \
        _Pragma("unroll")                                                          \
        for (int p = 0; p < 4; ++p) {                                              \
            gload16(aS + (size_t)(p * 64) * H_ + (kk), &sA[(buf) * 16384 + (p * 64 + wv8) * 64]); \
            gload16(bS + (size_t)(p * 64) * H_ + (kk), &sB[(buf) * 16384 + (p * 64 + wv8) * 64]); \
        }

    G2STAGE(0, 0)
    asm volatile("s_waitcnt vmcnt(0)" ::: "memory");
    __builtin_amdgcn_s_barrier();

    int cur = 0;
    for (int t = 0; t < H_ / 64; ++t) {
        if (t + 1 < H_ / 64) { G2STAGE(cur ^ 1, (t + 1) * 64) }
        hx8 bf[4][2];
        #pragma unroll
        for (int q = 0; q < 4; ++q) {
            hx8 af[2][2];
            #pragma unroll
            for (int mi = 0; mi < 2; ++mi)
                #pragma unroll
                for (int kh = 0; kh < 2; ++kh) {
                    const int R = wm * 128 + q * 32 + mi * 16 + fr;
                    af[mi][kh] = *(const hx8*)&sA[cur * 16384 + R * 64 + 8 * (((kh << 2) + q4) ^ (R & 7))];
                }
            if (q == 0) {
                #pragma unroll
                for (int ni = 0; ni < 4; ++ni)
                    #pragma unroll
                    for (int kh = 0; kh < 2; ++kh) {
                        const int Rc = wn * 64 + ni * 16 + fr;
                        bf[ni][kh] = *(const hx8*)&sB[cur * 16384 + Rc * 64 + 8 * (((kh << 2) + q4) ^ (Rc & 7))];
                    }
            }
            __builtin_amdgcn_s_setprio(1);
            #pragma unroll
            for (int ni = 0; ni < 4; ++ni)
                #pragma unroll
                for (int mi = 0; mi < 2; ++mi) {
                    acc[q * 2 + mi][ni] = __builtin_amdgcn_mfma_f32_16x16x32_f16(af[mi][0], bf[ni][0], acc[q * 2 + mi][ni], 0, 0, 0);
                    acc[q * 2 + mi][ni] = __builtin_amdgcn_mfma_f32_16x16x32_f16(af[mi][1], bf[ni][1], acc[q * 2 + mi][ni], 0, 0, 0);
                }
            __builtin_amdgcn_s_setprio(0);
        }
        asm volatile("s_waitcnt vmcnt(0)" ::: "memory");
        __builtin_amdgcn_s_barrier();
        cur ^= 1;
    }

    #pragma unroll
    for (int ni = 0; ni < 4; ++ni) {
        const int col = col0 + wn * 64 + ni * 16 + fr;
        const float bb = b2[(size_t)e * C_ + col];
        #pragma unroll
        for (int rf = 0; rf < 8; ++rf) {
            const int rowb = prow0 + wm * 128 + rf * 16 + q4 * 4;
            #pragma unroll
            for (int j = 0; j < 4; ++j)
                part[(size_t)(rowb + j) * C_ + col] = (_Float16)(acc[rf][ni][j] + bb);
        }
    }
    #undef G2STAGE
}

// ---------------- combine: out[t] = g0*part[inv0] + g1*part[inv1] ----------------
__global__ __launch_bounds__(256) void k_combine(
    const _Float16* __restrict__ part, const int* __restrict__ inv,
    const float* __restrict__ gate, float* __restrict__ out)
{
    const int bid = blockIdx.x;               // T_*2 blocks
    const int t = bid >> 1;
    const int c0 = ((bid & 1) << 11) + ((int)threadIdx.x << 3);
    const int p0 = inv[2 * t], p1 = inv[2 * t + 1];
    const float g0 = gate[p0], g1 = gate[p1];
    hx8 a = *(const hx8*)(part + (size_t)p0 * C_ + c0);
    hx8 b = *(const hx8*)(part + (size_t)p1 * C_ + c0);
    fx4 o0, o1;
    #pragma unroll
    for (int j = 0; j < 4; j++) {
        o0[j] = g0 * (float)a[j]     + g1 * (float)b[j];
        o1[j] = g0 * (float)a[4 + j] + g1 * (float)b[4 + j];
    }
    *(fx4*)(out + (size_t)t * C_ + c0)     = o0;
    *(fx4*)(out + (size_t)t * C_ + c0 + 4) = o1;
}

// ---------------- launch ----------------
extern "C" void kernel_launch(void* const* d_in, const int* in_sizes, int n_in,
                              void* d_out, int out_size, void* d_ws, size_t ws_size,
                              hipStream_t stream)
{
    const float* x  = (const float*)d_in[0];
    const float* sw = (const float*)d_in[1];
    const float* sb = (const float*)d_in[2];
    const float* w1 = (const float*)d_in[3];
    const float* b1 = (const float*)d_in[4];
    const float* w2 = (const float*)d_in[5];
    const float* b2 = (const float*)d_in[6];
    const float* w3 = (const float*)d_in[7];
    const float* b3 = (const float*)d_in[8];
    float* out = (float*)d_out;

    char* ws = (char*)d_ws;
    const size_t OFF_META = 0;                                    // 2048 B
    const size_t OFF_E0   = 2048;
    const size_t OFF_E1   = OFF_E0 + 4 * (size_t)T_;
    const size_t OFF_W0   = OFF_E1 + 4 * (size_t)T_;
    const size_t OFF_W1A  = OFF_W0 + 4 * (size_t)T_;
    const size_t OFF_TOK  = OFF_W1A + 4 * (size_t)T_;
    const size_t OFF_GATE = OFF_TOK + 4 * (size_t)PADROWS;
    const size_t OFF_INV  = OFF_GATE + 4 * (size_t)PADROWS;
    const size_t OFF_XH   = OFF_INV + 8 * (size_t)T_;
    const size_t OFF_HBUF = OFF_XH + 2 * (size_t)T_ * D_;
    // ALIAS region: w1h+w3h (live: routecvt..gemm1) overlaps part (live: gemm2..combine)
    const size_t OFF_ALIAS = OFF_HBUF + 2 * (size_t)PADROWS * H_;
    const size_t SZ_ALIAS  = 4 * (size_t)E_ * H_ * D_;            // 128 MiB
    const size_t OFF_W2H   = OFF_ALIAS + SZ_ALIAS;

    int*      meta  = (int*)(ws + OFF_META);
    int*      e0a   = (int*)(ws + OFF_E0);
    int*      e1a   = (int*)(ws + OFF_E1);
    float*    w0a   = (float*)(ws + OFF_W0);
    float*    w1a   = (float*)(ws + OFF_W1A);
    int*      tokb  = (int*)(ws + OFF_TOK);
    float*    gateb = (float*)(ws + OFF_GATE);
    int*      invb  = (int*)(ws + OFF_INV);
    _Float16* xh    = (_Float16*)(ws + OFF_XH);
    _Float16* hbuf  = (_Float16*)(ws + OFF_HBUF);
    _Float16* w1h   = (_Float16*)(ws + OFF_ALIAS);
    _Float16* w3h   = (_Float16*)(ws + OFF_ALIAS + 2 * (size_t)E_ * H_ * D_);
    _Float16* partb = (_Float16*)(ws + OFF_ALIAS);                // reuses w1h/w3h space
    _Float16* w2h   = (_Float16*)(ws + OFF_W2H);

    hipMemsetAsync(meta, 0, 2048, stream);
    hipMemsetAsync(tokb, 0, 4 * (size_t)PADROWS, stream);

    k_routecvt<<<NB_A, 256, 0, stream>>>(x, sw, sb, w1, w1h, w3, w3h, w2, w2h,
                                         xh, meta, e0a, e1a, w0a, w1a);
    k_scan<<<1, 1, 0, stream>>>(meta);
    k_scatter<<<(T_ + 255) / 256, 256, 0, stream>>>(meta, e0a, e1a, w0a, w1a,
                                                    tokb, gateb, invb);
    k_gemm1<<<8 * 32 * ((MAXRT256 + 7) / 8), 512, 131072, stream>>>(
        xh, w1h, b1, w3h, b3, meta, tokb, hbuf);
    k_gemm2<<<8 * 16 * ((MAXRT256 + 7) / 8), 512, 131072, stream>>>(
        hbuf, w2h, b2, meta, partb);
    k_combine<<<T_ * 2, 256, 0, stream>>>(partb, invb, gateb, out);
}